// Round 6
// baseline (203.053 us; speedup 1.0000x reference)
//
#include <hip/hip_runtime.h>

// ---------------------------------------------------------------------------
// DeepLagrangianNetwork head, MFMA v2 — no h1/h2 LDS round-trips.
//   h1 = lrelu(q@W1^T+b1)   computed per-lane DIRECTLY in A-fragment layout
//   h2 = lrelu(h1@W2^T+b2)  bf16 MFMA 16x16x32, acc stays fp32
//   heads (Ld0,Ld1,Lo)      in-register: 48 fma + shfl_xor butterfly (quad)
//   H = L L^T + 1e-9 I      epilogue on 4 lanes/quad, float4 store
// Block = 256 threads = 4 waves; wave w handles rows [blk*256+64w, +64).
// LDS: only W1 (64x4 f32) + b1 (64) = 1.3 KB. One barrier per block.
// Fragment layouts (m89/m120-verified):
//   A[m=lane&15][k=(lane>>4)*8+j]   B[k=(lane>>4)*8+j][n=lane&15]
//   C/D: n=lane&15, m=(lane>>4)*4+reg
// ---------------------------------------------------------------------------

typedef __attribute__((ext_vector_type(8))) short bf16x8;
typedef __attribute__((ext_vector_type(4))) float f32x4;

#define ROWS_PER_BLOCK 256

__device__ __forceinline__ float lrelu(float a) {
    return fmaxf(a, 0.01f * a);     // exact leaky_relu(0.01)
}

__device__ __forceinline__ float softplus(float v) {
    return fmaxf(v, 0.0f) + log1pf(expf(-fabsf(v)));   // jax.nn.softplus
}

__device__ __forceinline__ unsigned short bf16_rne(float f) {
    unsigned u = __float_as_uint(f);
    u += 0x7FFFu + ((u >> 16) & 1u);   // round-to-nearest-even
    return (unsigned short)(u >> 16);
}

__device__ __forceinline__ unsigned pk_bf16(float lo, float hi) {
    return (unsigned)bf16_rne(lo) | ((unsigned)bf16_rne(hi) << 16);
}

__device__ __forceinline__ float sel4(const float h[4], int c) {
    // h[c] for c in 0..3 without a dynamic index (3 cndmask)
    const float a = (c & 1) ? h[1] : h[0];
    const float b = (c & 1) ? h[3] : h[2];
    return (c & 2) ? b : a;
}

__global__ __launch_bounds__(256) void dln_mfma(
    const float* __restrict__ x,
    const float* __restrict__ W1,  const float* __restrict__ b1,
    const float* __restrict__ W2,  const float* __restrict__ b2,
    const float* __restrict__ WLd, const float* __restrict__ bLd,
    const float* __restrict__ WLo, const float* __restrict__ bLo,
    float* __restrict__ out)
{
    __shared__ __align__(16) float w1s[256];   // W1 row-major (64,4)
    __shared__ float b1s[64];

    const int tid  = threadIdx.x;
    const int lane = tid & 63;
    const int wv   = tid >> 6;
    const int quad = lane >> 4;
    const int col  = lane & 15;

    // ---- stage W1/b1 to LDS (broadcast source for A-frag builds) ----------
    w1s[tid] = W1[tid];                 // 256 elements, one per thread
    if (tid < 64) b1s[tid] = b1[tid];

    // ---- per-lane loop-invariant weights (L1/L2-hot global reads) ---------
    float wld0[4], wld1[4], wlo[4], b2c[4];
#pragma unroll
    for (int t = 0; t < 4; ++t) {
        const int n = 16 * t + col;
        wld0[t] = WLd[n];
        wld1[t] = WLd[64 + n];
        wlo[t]  = WLo[n];
        b2c[t]  = b2[n];
    }
    const float bld0 = bLd[0], bld1 = bLd[1], blo = bLo[0];

    // ---- B fragments from global W2 (16 KB, L1-hot; once per block) -------
    // B[k][n] = W2[n][k], n = 16t+col, k = 32s + 8*quad + j
    bf16x8 bfrag[4][2];
#pragma unroll
    for (int t = 0; t < 4; ++t) {
#pragma unroll
        for (int s = 0; s < 2; ++s) {
            const float* p = W2 + (16 * t + col) * 64 + 32 * s + 8 * quad;
            const float4 f0 = *(const float4*)(p);
            const float4 f1 = *(const float4*)(p + 4);
            uint4 u;
            u.x = pk_bf16(f0.x, f0.y);
            u.y = pk_bf16(f0.z, f0.w);
            u.z = pk_bf16(f1.x, f1.y);
            u.w = pk_bf16(f1.z, f1.w);
            bfrag[t][s] = __builtin_bit_cast(bf16x8, u);
        }
    }

    __syncthreads();   // w1s/b1s visible

    const int base = blockIdx.x * ROWS_PER_BLOCK + wv * 64;

#pragma unroll
    for (int mt = 0; mt < 4; ++mt) {
        const int rbase = base + mt * 16;       // global row of tile row 0

        // ---- q for this lane's A-row (m = col): rows rbase..rbase+15 ------
        const float4 q = ((const float4*)x)[rbase + col];

        // ---- build A-frags in-register: h1[k] for k = 32s + 8*quad + j ----
        unsigned au[8];
#pragma unroll
        for (int s = 0; s < 2; ++s) {
#pragma unroll
            for (int jj = 0; jj < 4; ++jj) {
                const int k0 = 32 * s + 8 * quad + 2 * jj;
                float h[2];
#pragma unroll
                for (int e = 0; e < 2; ++e) {
                    const int k = k0 + e;
                    const float4 w = *(const float4*)(w1s + 4 * k);
                    float a = b1s[k];
                    a = fmaf(q.x, w.x, a);
                    a = fmaf(q.y, w.y, a);
                    a = fmaf(q.z, w.z, a);
                    a = fmaf(q.w, w.w, a);
                    h[e] = lrelu(a);
                }
                au[s * 4 + jj] = pk_bf16(h[0], h[1]);
            }
        }
        const bf16x8 a0 = __builtin_bit_cast(bf16x8, make_uint4(au[0], au[1], au[2], au[3]));
        const bf16x8 a1 = __builtin_bit_cast(bf16x8, make_uint4(au[4], au[5], au[6], au[7]));

        // ---- layer 2: h2 tile (16x64) in fp32 accumulators ----------------
        f32x4 acc[4];
#pragma unroll
        for (int t = 0; t < 4; ++t) {
            acc[t] = (f32x4){b2c[t], b2c[t], b2c[t], b2c[t]};
            acc[t] = __builtin_amdgcn_mfma_f32_16x16x32_bf16(a0, bfrag[t][0], acc[t], 0, 0, 0);
            acc[t] = __builtin_amdgcn_mfma_f32_16x16x32_bf16(a1, bfrag[t][1], acc[t], 0, 0, 0);
        }

        // ---- heads: per row m=quad*4+r, partial over this lane's 4 cols ---
        float hd0[4], hd1[4], hdo[4];
#pragma unroll
        for (int r = 0; r < 4; ++r) {
            const float l0 = lrelu(acc[0][r]);
            const float l1 = lrelu(acc[1][r]);
            const float l2 = lrelu(acc[2][r]);
            const float l3 = lrelu(acc[3][r]);
            hd0[r] = fmaf(l3, wld0[3], fmaf(l2, wld0[2], fmaf(l1, wld0[1], l0 * wld0[0])));
            hd1[r] = fmaf(l3, wld1[3], fmaf(l2, wld1[2], fmaf(l1, wld1[1], l0 * wld1[0])));
            hdo[r] = fmaf(l3, wlo[3],  fmaf(l2, wlo[2],  fmaf(l1, wlo[1],  l0 * wlo[0])));
        }
        // butterfly-reduce across the 16 lanes of this quad group
#pragma unroll
        for (int m = 1; m < 16; m <<= 1) {
#pragma unroll
            for (int r = 0; r < 4; ++r) {
                hd0[r] += __shfl_xor(hd0[r], m, 16);
                hd1[r] += __shfl_xor(hd1[r], m, 16);
                hdo[r] += __shfl_xor(hdo[r], m, 16);
            }
        }

        // ---- epilogue: lane col<4 owns row rbase + quad*4 + col -----------
        if (col < 4) {
            const float ld0 = softplus(sel4(hd0, col) + bld0);
            const float ld1 = softplus(sel4(hd1, col) + bld1);
            const float lo  = sel4(hdo, col) + blo;
            float4 o;
            o.x = fmaf(ld0, ld0, 1e-9f);                  // H00
            o.y = ld0 * lo;                               // H01
            o.z = o.y;                                    // H10
            o.w = fmaf(lo, lo, fmaf(ld1, ld1, 1e-9f));    // H11
            reinterpret_cast<float4*>(out)[rbase + quad * 4 + col] = o;
        }
    }
}

// ---- scalar fallback for tail rows (nrows % 256) --------------------------
__global__ __launch_bounds__(256) void dln_tail(
    const float* __restrict__ x,
    const float* __restrict__ W1,  const float* __restrict__ b1,
    const float* __restrict__ W2,  const float* __restrict__ b2,
    const float* __restrict__ WLd, const float* __restrict__ bLd,
    const float* __restrict__ WLo, const float* __restrict__ bLo,
    float* __restrict__ out, int row0, int nrows)
{
    const int row = row0 + blockIdx.x * 256 + threadIdx.x;
    if (row >= nrows) return;
    const float4 qv = reinterpret_cast<const float4*>(x)[row];
    float h1[64];
#pragma unroll
    for (int j = 0; j < 64; ++j) {
        float a = b1[j];
        a = fmaf(qv.x, W1[4 * j + 0], a);
        a = fmaf(qv.y, W1[4 * j + 1], a);
        a = fmaf(qv.z, W1[4 * j + 2], a);
        a = fmaf(qv.w, W1[4 * j + 3], a);
        h1[j] = lrelu(a);
    }
    float ld0 = bLd[0], ld1 = bLd[1], lo = bLo[0];
#pragma unroll 4
    for (int j = 0; j < 64; ++j) {
        float a0 = b2[j], a1 = 0.0f;
        const float* w = W2 + 64 * j;
#pragma unroll
        for (int k = 0; k < 64; k += 2) {
            a0 = fmaf(h1[k],     w[k],     a0);
            a1 = fmaf(h1[k + 1], w[k + 1], a1);
        }
        const float a = lrelu(a0 + a1);
        ld0 = fmaf(a, WLd[j],      ld0);
        ld1 = fmaf(a, WLd[64 + j], ld1);
        lo  = fmaf(a, WLo[j],      lo);
    }
    ld0 = softplus(ld0);
    ld1 = softplus(ld1);
    float4 o;
    o.x = fmaf(ld0, ld0, 1e-9f);
    o.y = ld0 * lo;
    o.z = o.y;
    o.w = fmaf(lo, lo, fmaf(ld1, ld1, 1e-9f));
    reinterpret_cast<float4*>(out)[row] = o;
}

extern "C" void kernel_launch(void* const* d_in, const int* in_sizes, int n_in,
                              void* d_out, int out_size, void* d_ws, size_t ws_size,
                              hipStream_t stream)
{
    const float* x   = (const float*)d_in[0];
    const float* W1  = (const float*)d_in[1];
    const float* b1  = (const float*)d_in[2];
    const float* W2  = (const float*)d_in[3];
    const float* b2  = (const float*)d_in[4];
    const float* WLd = (const float*)d_in[5];
    const float* bLd = (const float*)d_in[6];
    const float* WLo = (const float*)d_in[7];
    const float* bLo = (const float*)d_in[8];
    float* out = (float*)d_out;

    const int nrows = in_sizes[0] / 4;             // x is (nrows, 4) fp32
    const int nfull = nrows / ROWS_PER_BLOCK;
    const int rem   = nrows - nfull * ROWS_PER_BLOCK;

    if (nfull > 0)
        dln_mfma<<<nfull, 256, 0, stream>>>(
            x, W1, b1, W2, b2, WLd, bLd, WLo, bLo, out);
    if (rem > 0)
        dln_tail<<<(rem + 255) / 256, 256, 0, stream>>>(
            x, W1, b1, W2, b2, WLd, bLd, WLo, bLo, out,
            nfull * ROWS_PER_BLOCK, nrows);
}

// Round 7
// 158.732 us; speedup vs baseline: 1.2792x; 1.2792x over previous
//
#include <hip/hip_runtime.h>

// ---------------------------------------------------------------------------
// DeepLagrangianNetwork head, MFMA v3.
//   phase 1: h1 = lrelu(q@W1^T+b1), thread-per-row, packed bf16 ->
//            XOR-swizzled LDS (stride 64 shorts, 16B-block kblk^=(row&7):
//            conflict-free b128 writes AND reads).
//   phase 2: h2 = lrelu(h1@W2^T+b2) via bf16 MFMA 16x16x32, fp32 acc.
//   heads:   per-lane partials over 4 cols + DPP row_ror rotate-add
//            reduction across the 16-lane quad group (pure VALU, no DS).
//   epilogue: H = L L^T + 1e-9 I on lanes col<4, float4 store.
// Block = 256 threads = 4 waves; wave w owns rows [blk*256+64w, +64).
// No __syncthreads: h1 write->read is same-wave (LDS ops in order, R5-proven).
// Fragment layouts (m89-verified, R5/R6-validated):
//   A[m=lane&15][k=(lane>>4)*8+j] (+32 for 2nd mfma)
//   B[k][n=lane&15]   C/D: n=lane&15, m=(lane>>4)*4+reg
// ---------------------------------------------------------------------------

typedef __attribute__((ext_vector_type(8))) short bf16x8;
typedef __attribute__((ext_vector_type(4))) float f32x4;

#define ROWS_PER_BLOCK 256

__device__ __forceinline__ float lrelu(float a) {
    return fmaxf(a, 0.01f * a);     // exact leaky_relu(0.01)
}

__device__ __forceinline__ float softplus(float v) {
    return fmaxf(v, 0.0f) + log1pf(expf(-fabsf(v)));   // jax.nn.softplus
}

__device__ __forceinline__ unsigned short bf16_rne(float f) {
    unsigned u = __float_as_uint(f);
    u += 0x7FFFu + ((u >> 16) & 1u);   // round-to-nearest-even
    return (unsigned short)(u >> 16);
}

__device__ __forceinline__ unsigned pk_bf16(float lo, float hi) {
    return (unsigned)bf16_rne(lo) | ((unsigned)bf16_rne(hi) << 16);
}

__device__ __forceinline__ float sel4(const float h[4], int c) {
    const float a = (c & 1) ? h[1] : h[0];
    const float b = (c & 1) ? h[3] : h[2];
    return (c & 2) ? b : a;
}

// rotate-add over the 16-lane DPP row (our quad group): after ror 1,2,4,8
// every lane holds the full 16-lane sum. Pure VALU (v_mov_dpp + v_add).
#define DPP_ROR_ADD(v, CTRL)                                                   \
    v += __builtin_bit_cast(float, __builtin_amdgcn_update_dpp(                \
            __builtin_bit_cast(int, v), __builtin_bit_cast(int, v),            \
            (CTRL), 0xF, 0xF, false))

__device__ __forceinline__ void quad16_sum(float& v) {
    DPP_ROR_ADD(v, 0x121);   // row_ror:1
    DPP_ROR_ADD(v, 0x122);   // row_ror:2
    DPP_ROR_ADD(v, 0x124);   // row_ror:4
    DPP_ROR_ADD(v, 0x128);   // row_ror:8
}

__global__ __launch_bounds__(256) void dln_mfma(
    const float* __restrict__ x,
    const float* __restrict__ W1,  const float* __restrict__ b1,
    const float* __restrict__ W2,  const float* __restrict__ b2,
    const float* __restrict__ WLd, const float* __restrict__ bLd,
    const float* __restrict__ WLo, const float* __restrict__ bLo,
    float* __restrict__ out)
{
    // h1: 256 rows x 64 shorts (128 B), 16B-block-XOR swizzled -> 32 KB
    __shared__ __align__(16) unsigned short h1s[ROWS_PER_BLOCK * 64];

    const int tid  = threadIdx.x;
    const int lane = tid & 63;
    const int wv   = tid >> 6;
    const int quad = lane >> 4;
    const int col  = lane & 15;

    // ---- loop-invariant per-lane weights (L1-hot global; once/block) ------
    float wld0[4], wld1[4], wlo[4], b2c[4];
#pragma unroll
    for (int t = 0; t < 4; ++t) {
        const int n = 16 * t + col;
        wld0[t] = WLd[n];
        wld1[t] = WLd[64 + n];
        wlo[t]  = WLo[n];
        b2c[t]  = b2[n];
    }
    const float bld0 = bLd[0], bld1 = bLd[1], blo = bLo[0];

    // ---- B fragments from global W2 (16 KB, L1-hot) -----------------------
    // B[k][n] = W2[n][k], n = 16t+col, k = 32s + 8*quad + j
    bf16x8 bfrag[4][2];
#pragma unroll
    for (int t = 0; t < 4; ++t) {
#pragma unroll
        for (int s = 0; s < 2; ++s) {
            const float* p = W2 + (16 * t + col) * 64 + 32 * s + 8 * quad;
            const float4 f0 = *(const float4*)(p);
            const float4 f1 = *(const float4*)(p + 4);
            uint4 u;
            u.x = pk_bf16(f0.x, f0.y);
            u.y = pk_bf16(f0.z, f0.w);
            u.z = pk_bf16(f1.x, f1.y);
            u.w = pk_bf16(f1.z, f1.w);
            bfrag[t][s] = __builtin_bit_cast(bf16x8, u);
        }
    }

    // ---- phase 1: h1 for row = tid, packed bf16 -> swizzled LDS -----------
    {
        const int row_g = blockIdx.x * ROWS_PER_BLOCK + tid;
        const float4 qv = ((const float4*)x)[row_g];
        unsigned short* myrow = h1s + tid * 64;
        const int sw = tid & 7;                     // row XOR key
#pragma unroll
        for (int blk = 0; blk < 8; ++blk) {
            unsigned up[4];
#pragma unroll
            for (int p = 0; p < 4; ++p) {
                float h[2];
#pragma unroll
                for (int e = 0; e < 2; ++e) {
                    const int j = blk * 8 + p * 2 + e;
                    float a = b1[j];
                    a = fmaf(qv.x, W1[4 * j + 0], a);
                    a = fmaf(qv.y, W1[4 * j + 1], a);
                    a = fmaf(qv.z, W1[4 * j + 2], a);
                    a = fmaf(qv.w, W1[4 * j + 3], a);
                    h[e] = lrelu(a);
                }
                up[p] = pk_bf16(h[0], h[1]);
            }
            *(uint4*)(myrow + ((blk ^ sw) << 3)) = make_uint4(up[0], up[1], up[2], up[3]);
        }
    }
    // No barrier: wave w reads only rows [w*64, w*64+64) it wrote itself;
    // same-wave LDS ops complete in order (validated round 5).

    const int gbase = blockIdx.x * ROWS_PER_BLOCK + wv * 64;

#pragma unroll
    for (int mt = 0; mt < 4; ++mt) {
        const int lrow = wv * 64 + mt * 16 + col;   // block-relative A-row
        // ---- A fragments (swizzled, conflict-free) ------------------------
        const unsigned short* rowp = h1s + lrow * 64;
        const int sw = col & 7;                     // (lrow & 7) == (col & 7)
        const uint4 a0u = *(const uint4*)(rowp + (((quad)     ^ sw) << 3));
        const uint4 a1u = *(const uint4*)(rowp + (((quad + 4) ^ sw) << 3));
        const bf16x8 a0 = __builtin_bit_cast(bf16x8, a0u);
        const bf16x8 a1 = __builtin_bit_cast(bf16x8, a1u);

        // ---- layer 2: h2 tile (16x64), fp32 accumulators ------------------
        f32x4 acc[4];
#pragma unroll
        for (int t = 0; t < 4; ++t) {
            acc[t] = (f32x4){b2c[t], b2c[t], b2c[t], b2c[t]};
            acc[t] = __builtin_amdgcn_mfma_f32_16x16x32_bf16(a0, bfrag[t][0], acc[t], 0, 0, 0);
            acc[t] = __builtin_amdgcn_mfma_f32_16x16x32_bf16(a1, bfrag[t][1], acc[t], 0, 0, 0);
        }

        // ---- heads: partials over this lane's 4 cols, DPP 16-lane sum -----
        float hd0[4], hd1[4], hdo[4];
#pragma unroll
        for (int r = 0; r < 4; ++r) {
            const float l0 = lrelu(acc[0][r]);
            const float l1 = lrelu(acc[1][r]);
            const float l2 = lrelu(acc[2][r]);
            const float l3 = lrelu(acc[3][r]);
            hd0[r] = fmaf(l3, wld0[3], fmaf(l2, wld0[2], fmaf(l1, wld0[1], l0 * wld0[0])));
            hd1[r] = fmaf(l3, wld1[3], fmaf(l2, wld1[2], fmaf(l1, wld1[1], l0 * wld1[0])));
            hdo[r] = fmaf(l3, wlo[3],  fmaf(l2, wlo[2],  fmaf(l1, wlo[1],  l0 * wlo[0])));
            quad16_sum(hd0[r]);
            quad16_sum(hd1[r]);
            quad16_sum(hdo[r]);
        }

        // ---- epilogue: lane col<4 owns row (quad*4 + col) -----------------
        if (col < 4) {
            const float ld0 = softplus(sel4(hd0, col) + bld0);
            const float ld1 = softplus(sel4(hd1, col) + bld1);
            const float lo  = sel4(hdo, col) + blo;
            float4 o;
            o.x = fmaf(ld0, ld0, 1e-9f);                  // H00
            o.y = ld0 * lo;                               // H01
            o.z = o.y;                                    // H10
            o.w = fmaf(lo, lo, fmaf(ld1, ld1, 1e-9f));    // H11
            reinterpret_cast<float4*>(out)[gbase + mt * 16 + quad * 4 + col] = o;
        }
    }
}

// ---- scalar fallback for tail rows (nrows % 256) --------------------------
__global__ __launch_bounds__(256) void dln_tail(
    const float* __restrict__ x,
    const float* __restrict__ W1,  const float* __restrict__ b1,
    const float* __restrict__ W2,  const float* __restrict__ b2,
    const float* __restrict__ WLd, const float* __restrict__ bLd,
    const float* __restrict__ WLo, const float* __restrict__ bLo,
    float* __restrict__ out, int row0, int nrows)
{
    const int row = row0 + blockIdx.x * 256 + threadIdx.x;
    if (row >= nrows) return;
    const float4 qv = reinterpret_cast<const float4*>(x)[row];
    float h1[64];
#pragma unroll
    for (int j = 0; j < 64; ++j) {
        float a = b1[j];
        a = fmaf(qv.x, W1[4 * j + 0], a);
        a = fmaf(qv.y, W1[4 * j + 1], a);
        a = fmaf(qv.z, W1[4 * j + 2], a);
        a = fmaf(qv.w, W1[4 * j + 3], a);
        h1[j] = lrelu(a);
    }
    float ld0 = bLd[0], ld1 = bLd[1], lo = bLo[0];
#pragma unroll 4
    for (int j = 0; j < 64; ++j) {
        float a0 = b2[j], a1 = 0.0f;
        const float* w = W2 + 64 * j;
#pragma unroll
        for (int k = 0; k < 64; k += 2) {
            a0 = fmaf(h1[k],     w[k],     a0);
            a1 = fmaf(h1[k + 1], w[k + 1], a1);
        }
        const float a = lrelu(a0 + a1);
        ld0 = fmaf(a, WLd[j],      ld0);
        ld1 = fmaf(a, WLd[64 + j], ld1);
        lo  = fmaf(a, WLo[j],      lo);
    }
    ld0 = softplus(ld0);
    ld1 = softplus(ld1);
    float4 o;
    o.x = fmaf(ld0, ld0, 1e-9f);
    o.y = ld0 * lo;
    o.z = o.y;
    o.w = fmaf(lo, lo, fmaf(ld1, ld1, 1e-9f));
    reinterpret_cast<float4*>(out)[row] = o;
}

extern "C" void kernel_launch(void* const* d_in, const int* in_sizes, int n_in,
                              void* d_out, int out_size, void* d_ws, size_t ws_size,
                              hipStream_t stream)
{
    const float* x   = (const float*)d_in[0];
    const float* W1  = (const float*)d_in[1];
    const float* b1  = (const float*)d_in[2];
    const float* W2  = (const float*)d_in[3];
    const float* b2  = (const float*)d_in[4];
    const float* WLd = (const float*)d_in[5];
    const float* bLd = (const float*)d_in[6];
    const float* WLo = (const float*)d_in[7];
    const float* bLo = (const float*)d_in[8];
    float* out = (float*)d_out;

    const int nrows = in_sizes[0] / 4;             // x is (nrows, 4) fp32
    const int nfull = nrows / ROWS_PER_BLOCK;
    const int rem   = nrows - nfull * ROWS_PER_BLOCK;

    if (nfull > 0)
        dln_mfma<<<nfull, 256, 0, stream>>>(
            x, W1, b1, W2, b2, WLd, bLd, WLo, bLo, out);
    if (rem > 0)
        dln_tail<<<(rem + 255) / 256, 256, 0, stream>>>(
            x, W1, b1, W2, b2, WLd, bLd, WLo, bLo, out,
            nfull * ROWS_PER_BLOCK, nrows);
}

// Round 8
// 154.681 us; speedup vs baseline: 1.3127x; 1.0262x over previous
//
#include <hip/hip_runtime.h>

// ---------------------------------------------------------------------------
// DeepLagrangianNetwork head, MFMA v4 (= v3 with spill strangled).
//   phase 1: h1 = lrelu(q@W1^T+b1), thread-per-row, packed bf16 ->
//            XOR-swizzled LDS (stride 64 shorts; 16B-block blk^=(row&7):
//            measured 0 bank conflicts in R7).
//   phase 2: h2 = lrelu(h1@W2^T+b2) via bf16 MFMA 16x16x32, fp32 acc.
//   heads:   per-lane partials over 4 cols + DPP row_ror rotate-add
//            reduction across the 16-lane quad group (pure VALU).
//   epilogue: H = L L^T + 1e-9 I on lanes col<4, float4 store.
// Anti-spill measures (R7 post-mortem: WRITE_SIZE +39MB = scratch spill):
//   - __syncthreads() restored between phases (scheduling fence);
//   - bfrag/head-weight loads AFTER phase 1 (not live across it);
//   - __launch_bounds__(256,2) -> VGPR cap 256;
//   - #pragma unroll 1 on the mt loop (one tile's temps live at a time).
// Fragment layouts (m89-verified, R5/R6/R7-validated):
//   A[m=lane&15][k=(lane>>4)*8+j] (+32 for 2nd mfma)
//   B[k][n=lane&15]   C/D: n=lane&15, m=(lane>>4)*4+reg
// ---------------------------------------------------------------------------

typedef __attribute__((ext_vector_type(8))) short bf16x8;
typedef __attribute__((ext_vector_type(4))) float f32x4;

#define ROWS_PER_BLOCK 256

__device__ __forceinline__ float lrelu(float a) {
    return fmaxf(a, 0.01f * a);     // exact leaky_relu(0.01)
}

__device__ __forceinline__ float softplus(float v) {
    return fmaxf(v, 0.0f) + log1pf(expf(-fabsf(v)));   // jax.nn.softplus
}

__device__ __forceinline__ unsigned short bf16_rne(float f) {
    unsigned u = __float_as_uint(f);
    u += 0x7FFFu + ((u >> 16) & 1u);   // round-to-nearest-even
    return (unsigned short)(u >> 16);
}

__device__ __forceinline__ unsigned pk_bf16(float lo, float hi) {
    return (unsigned)bf16_rne(lo) | ((unsigned)bf16_rne(hi) << 16);
}

__device__ __forceinline__ float sel4(const float h[4], int c) {
    const float a = (c & 1) ? h[1] : h[0];
    const float b = (c & 1) ? h[3] : h[2];
    return (c & 2) ? b : a;
}

// rotate-add over the 16-lane DPP row (our quad group): after ror 1,2,4,8
// every lane holds the full 16-lane sum. Pure VALU (v_mov_dpp + v_add).
#define DPP_ROR_ADD(v, CTRL)                                                   \
    v += __builtin_bit_cast(float, __builtin_amdgcn_update_dpp(                \
            __builtin_bit_cast(int, v), __builtin_bit_cast(int, v),            \
            (CTRL), 0xF, 0xF, false))

__device__ __forceinline__ void quad16_sum(float& v) {
    DPP_ROR_ADD(v, 0x121);   // row_ror:1
    DPP_ROR_ADD(v, 0x122);   // row_ror:2
    DPP_ROR_ADD(v, 0x124);   // row_ror:4
    DPP_ROR_ADD(v, 0x128);   // row_ror:8
}

__global__ __launch_bounds__(256, 2) void dln_mfma(
    const float* __restrict__ x,
    const float* __restrict__ W1,  const float* __restrict__ b1,
    const float* __restrict__ W2,  const float* __restrict__ b2,
    const float* __restrict__ WLd, const float* __restrict__ bLd,
    const float* __restrict__ WLo, const float* __restrict__ bLo,
    float* __restrict__ out)
{
    // h1: 256 rows x 64 shorts (128 B), 16B-block-XOR swizzled -> 32 KB
    __shared__ __align__(16) unsigned short h1s[ROWS_PER_BLOCK * 64];

    const int tid  = threadIdx.x;
    const int lane = tid & 63;
    const int wv   = tid >> 6;
    const int quad = lane >> 4;
    const int col  = lane & 15;

    // ---- phase 1: h1 for row = tid, packed bf16 -> swizzled LDS -----------
    {
        const int row_g = blockIdx.x * ROWS_PER_BLOCK + tid;
        const float4 qv = ((const float4*)x)[row_g];
        unsigned short* myrow = h1s + tid * 64;
        const int sw = tid & 7;                     // row XOR key
#pragma unroll
        for (int blk = 0; blk < 8; ++blk) {
            unsigned up[4];
#pragma unroll
            for (int p = 0; p < 4; ++p) {
                float h[2];
#pragma unroll
                for (int e = 0; e < 2; ++e) {
                    const int j = blk * 8 + p * 2 + e;
                    float a = b1[j];
                    a = fmaf(qv.x, W1[4 * j + 0], a);
                    a = fmaf(qv.y, W1[4 * j + 1], a);
                    a = fmaf(qv.z, W1[4 * j + 2], a);
                    a = fmaf(qv.w, W1[4 * j + 3], a);
                    h[e] = lrelu(a);
                }
                up[p] = pk_bf16(h[0], h[1]);
            }
            *(uint4*)(myrow + ((blk ^ sw) << 3)) = make_uint4(up[0], up[1], up[2], up[3]);
        }
    }

    // ---- loop-invariant per-lane weights (loaded AFTER phase 1) -----------
    float wld0[4], wld1[4], wlo[4], b2c[4];
#pragma unroll
    for (int t = 0; t < 4; ++t) {
        const int n = 16 * t + col;
        wld0[t] = WLd[n];
        wld1[t] = WLd[64 + n];
        wlo[t]  = WLo[n];
        b2c[t]  = b2[n];
    }
    const float bld0 = bLd[0], bld1 = bLd[1], blo = bLo[0];

    // ---- B fragments from global W2 (16 KB, L1-hot) -----------------------
    // B[k][n] = W2[n][k], n = 16t+col, k = 32s + 8*quad + j
    bf16x8 bfrag[4][2];
#pragma unroll
    for (int t = 0; t < 4; ++t) {
#pragma unroll
        for (int s = 0; s < 2; ++s) {
            const float* p = W2 + (16 * t + col) * 64 + 32 * s + 8 * quad;
            const float4 f0 = *(const float4*)(p);
            const float4 f1 = *(const float4*)(p + 4);
            uint4 u;
            u.x = pk_bf16(f0.x, f0.y);
            u.y = pk_bf16(f0.z, f0.w);
            u.z = pk_bf16(f1.x, f1.y);
            u.w = pk_bf16(f1.z, f1.w);
            bfrag[t][s] = __builtin_bit_cast(bf16x8, u);
        }
    }

    __syncthreads();   // scheduling fence; h1 fully visible

    const int gbase = blockIdx.x * ROWS_PER_BLOCK + wv * 64;

#pragma unroll 1
    for (int mt = 0; mt < 4; ++mt) {
        const int lrow = wv * 64 + mt * 16 + col;   // block-relative A-row
        // ---- A fragments (swizzled, conflict-free: R7 measured 0) ---------
        const unsigned short* rowp = h1s + lrow * 64;
        const int sw = col & 7;                     // (lrow & 7) == (col & 7)
        const uint4 a0u = *(const uint4*)(rowp + (((quad)     ^ sw) << 3));
        const uint4 a1u = *(const uint4*)(rowp + (((quad + 4) ^ sw) << 3));
        const bf16x8 a0 = __builtin_bit_cast(bf16x8, a0u);
        const bf16x8 a1 = __builtin_bit_cast(bf16x8, a1u);

        // ---- layer 2: h2 tile (16x64), fp32 accumulators ------------------
        f32x4 acc[4];
#pragma unroll
        for (int t = 0; t < 4; ++t) {
            acc[t] = (f32x4){b2c[t], b2c[t], b2c[t], b2c[t]};
            acc[t] = __builtin_amdgcn_mfma_f32_16x16x32_bf16(a0, bfrag[t][0], acc[t], 0, 0, 0);
            acc[t] = __builtin_amdgcn_mfma_f32_16x16x32_bf16(a1, bfrag[t][1], acc[t], 0, 0, 0);
        }

        // ---- heads: partials over this lane's 4 cols, DPP 16-lane sum -----
        float hd0[4], hd1[4], hdo[4];
#pragma unroll
        for (int r = 0; r < 4; ++r) {
            const float l0 = lrelu(acc[0][r]);
            const float l1 = lrelu(acc[1][r]);
            const float l2 = lrelu(acc[2][r]);
            const float l3 = lrelu(acc[3][r]);
            hd0[r] = fmaf(l3, wld0[3], fmaf(l2, wld0[2], fmaf(l1, wld0[1], l0 * wld0[0])));
            hd1[r] = fmaf(l3, wld1[3], fmaf(l2, wld1[2], fmaf(l1, wld1[1], l0 * wld1[0])));
            hdo[r] = fmaf(l3, wlo[3],  fmaf(l2, wlo[2],  fmaf(l1, wlo[1],  l0 * wlo[0])));
            quad16_sum(hd0[r]);
            quad16_sum(hd1[r]);
            quad16_sum(hdo[r]);
        }

        // ---- epilogue: lane col<4 owns row (quad*4 + col) -----------------
        if (col < 4) {
            const float ld0 = softplus(sel4(hd0, col) + bld0);
            const float ld1 = softplus(sel4(hd1, col) + bld1);
            const float lo  = sel4(hdo, col) + blo;
            float4 o;
            o.x = fmaf(ld0, ld0, 1e-9f);                  // H00
            o.y = ld0 * lo;                               // H01
            o.z = o.y;                                    // H10
            o.w = fmaf(lo, lo, fmaf(ld1, ld1, 1e-9f));    // H11
            reinterpret_cast<float4*>(out)[gbase + mt * 16 + quad * 4 + col] = o;
        }
    }
}

// ---- scalar fallback for tail rows (nrows % 256) --------------------------
__global__ __launch_bounds__(256) void dln_tail(
    const float* __restrict__ x,
    const float* __restrict__ W1,  const float* __restrict__ b1,
    const float* __restrict__ W2,  const float* __restrict__ b2,
    const float* __restrict__ WLd, const float* __restrict__ bLd,
    const float* __restrict__ WLo, const float* __restrict__ bLo,
    float* __restrict__ out, int row0, int nrows)
{
    const int row = row0 + blockIdx.x * 256 + threadIdx.x;
    if (row >= nrows) return;
    const float4 qv = reinterpret_cast<const float4*>(x)[row];
    float h1[64];
#pragma unroll
    for (int j = 0; j < 64; ++j) {
        float a = b1[j];
        a = fmaf(qv.x, W1[4 * j + 0], a);
        a = fmaf(qv.y, W1[4 * j + 1], a);
        a = fmaf(qv.z, W1[4 * j + 2], a);
        a = fmaf(qv.w, W1[4 * j + 3], a);
        h1[j] = lrelu(a);
    }
    float ld0 = bLd[0], ld1 = bLd[1], lo = bLo[0];
#pragma unroll 4
    for (int j = 0; j < 64; ++j) {
        float a0 = b2[j], a1 = 0.0f;
        const float* w = W2 + 64 * j;
#pragma unroll
        for (int k = 0; k < 64; k += 2) {
            a0 = fmaf(h1[k],     w[k],     a0);
            a1 = fmaf(h1[k + 1], w[k + 1], a1);
        }
        const float a = lrelu(a0 + a1);
        ld0 = fmaf(a, WLd[j],      ld0);
        ld1 = fmaf(a, WLd[64 + j], ld1);
        lo  = fmaf(a, WLo[j],      lo);
    }
    ld0 = softplus(ld0);
    ld1 = softplus(ld1);
    float4 o;
    o.x = fmaf(ld0, ld0, 1e-9f);
    o.y = ld0 * lo;
    o.z = o.y;
    o.w = fmaf(lo, lo, fmaf(ld1, ld1, 1e-9f));
    reinterpret_cast<float4*>(out)[row] = o;
}

extern "C" void kernel_launch(void* const* d_in, const int* in_sizes, int n_in,
                              void* d_out, int out_size, void* d_ws, size_t ws_size,
                              hipStream_t stream)
{
    const float* x   = (const float*)d_in[0];
    const float* W1  = (const float*)d_in[1];
    const float* b1  = (const float*)d_in[2];
    const float* W2  = (const float*)d_in[3];
    const float* b2  = (const float*)d_in[4];
    const float* WLd = (const float*)d_in[5];
    const float* bLd = (const float*)d_in[6];
    const float* WLo = (const float*)d_in[7];
    const float* bLo = (const float*)d_in[8];
    float* out = (float*)d_out;

    const int nrows = in_sizes[0] / 4;             // x is (nrows, 4) fp32
    const int nfull = nrows / ROWS_PER_BLOCK;
    const int rem   = nrows - nfull * ROWS_PER_BLOCK;

    if (nfull > 0)
        dln_mfma<<<nfull, 256, 0, stream>>>(
            x, W1, b1, W2, b2, WLd, bLd, WLo, bLo, out);
    if (rem > 0)
        dln_tail<<<(rem + 255) / 256, 256, 0, stream>>>(
            x, W1, b1, W2, b2, WLd, bLd, WLo, bLo, out,
            nfull * ROWS_PER_BLOCK, nrows);
}

// Round 9
// 138.888 us; speedup vs baseline: 1.4620x; 1.1137x over previous
//
#include <hip/hip_runtime.h>

// ---------------------------------------------------------------------------
// DeepLagrangianNetwork head, MFMA v5 (R5 skeleton, heads restructured).
//   prologue: W2 -> LDS -> bf16 B-frags (R5-proven); head weights per-lane.
//   phase 1:  h1 = lrelu(q@W1^T+b1), thread-per-row, packed bf16 ->
//             XOR-swizzled LDS (stride 64 shorts; R7-measured 0 conflicts).
//   mt loop (per wave, 4 tiles of 16 rows):
//     A-frags from swizzled LDS (R7-proven) -> 8x mfma_16x16x32_bf16 (fp32 acc)
//     head partials per lane (R6/R7-proven fma code) -> fp32 LDS slab
//     (stride 52 dwords; banks: writes 2-way, reads ~4-way)
//     48 lanes reduce 16 cols; regroup via 1KB slab2; 16 lanes: softplus +
//     H = L L^T + 1e-9 I, coalesced 256B float4 store.
//   h2 never materialized/quantized; no barriers after prologue; no DPP/shfl.
// Fragment layouts (m89-verified, R5/R6/R7-validated):
//   A[m=lane&15][k=(lane>>4)*8+j] (+32)   B[k][n=lane&15]
//   C/D: n=lane&15, m=(lane>>4)*4+reg
// ---------------------------------------------------------------------------

typedef __attribute__((ext_vector_type(8))) short bf16x8;
typedef __attribute__((ext_vector_type(4))) float f32x4;

#define ROWS_PER_BLOCK 256
#define PSTRIDE 52                     // dwords per partial row (16B-aligned)
#define PW (PSTRIDE * 16)              // 832 dwords per wave

__device__ __forceinline__ float lrelu(float a) {
    return fmaxf(a, 0.01f * a);        // exact leaky_relu(0.01)
}

__device__ __forceinline__ float softplus(float v) {
    return fmaxf(v, 0.0f) + log1pf(expf(-fabsf(v)));   // jax.nn.softplus
}

__device__ __forceinline__ unsigned short bf16_rne(float f) {
    unsigned u = __float_as_uint(f);
    u += 0x7FFFu + ((u >> 16) & 1u);   // round-to-nearest-even
    return (unsigned short)(u >> 16);
}

__device__ __forceinline__ unsigned pk_bf16(float lo, float hi) {
    return (unsigned)bf16_rne(lo) | ((unsigned)bf16_rne(hi) << 16);
}

__global__ __launch_bounds__(256) void dln_mfma(
    const float* __restrict__ x,
    const float* __restrict__ W1,  const float* __restrict__ b1,
    const float* __restrict__ W2,  const float* __restrict__ b2,
    const float* __restrict__ WLd, const float* __restrict__ bLd,
    const float* __restrict__ WLo, const float* __restrict__ bLo,
    float* __restrict__ out)
{
    // h1: 256 rows x 64 shorts, XOR-swizzled (32 KB). Also stages W2 (16 KB).
    __shared__ __align__(16) unsigned short h1s[ROWS_PER_BLOCK * 64];
    // per-wave head-partial slab: 16 rows x (3 heads x 16 cols), stride 52
    __shared__ __align__(16) float psum[4 * PW];          // 13312 B
    // per-wave regroup slab: 16 rows x 4
    __shared__ float s2[4 * 64];                          // 1 KB

    const int tid  = threadIdx.x;
    const int lane = tid & 63;
    const int wv   = tid >> 6;
    const int quad = lane >> 4;
    const int col  = lane & 15;

    // ---- prologue: stage W2 (fp32, 16 KB) into h1s region -----------------
    {
        const float4* src = (const float4*)W2;            // 1024 float4
        float4*       dst = (float4*)h1s;
#pragma unroll
        for (int i = 0; i < 4; ++i)
            dst[tid + 256 * i] = src[tid + 256 * i];
    }
    // per-lane loop invariants
    float wld0[4], wld1[4], wlo[4], b2c[4];
#pragma unroll
    for (int t = 0; t < 4; ++t) {
        const int n = 16 * t + col;
        wld0[t] = WLd[n];
        wld1[t] = WLd[64 + n];
        wlo[t]  = WLo[n];
        b2c[t]  = b2[n];
    }
    const float bld0 = bLd[0], bld1 = bLd[1], blo = bLo[0];
    __syncthreads();

    // ---- B fragments from LDS-staged W2 (R5-proven) -----------------------
    bf16x8 bfrag[4][2];
    {
        const float* w2l = (const float*)h1s;
#pragma unroll
        for (int t = 0; t < 4; ++t) {
#pragma unroll
            for (int s = 0; s < 2; ++s) {
                const float* p = w2l + (16 * t + col) * 64 + 32 * s + 8 * quad;
                const float4 f0 = *(const float4*)(p);
                const float4 f1 = *(const float4*)(p + 4);
                uint4 u;
                u.x = pk_bf16(f0.x, f0.y);
                u.y = pk_bf16(f0.z, f0.w);
                u.z = pk_bf16(f1.x, f1.y);
                u.w = pk_bf16(f1.z, f1.w);
                bfrag[t][s] = __builtin_bit_cast(bf16x8, u);
            }
        }
    }
    __syncthreads();   // W2 region about to be overwritten by h1

    // ---- phase 1: h1 for row = tid, packed bf16 -> swizzled LDS -----------
    {
        const int row_g = blockIdx.x * ROWS_PER_BLOCK + tid;
        const float4 qv = ((const float4*)x)[row_g];
        unsigned short* myrow = h1s + tid * 64;
        const int sw = tid & 7;                     // row XOR key
#pragma unroll
        for (int blk = 0; blk < 8; ++blk) {
            unsigned up[4];
#pragma unroll
            for (int p = 0; p < 4; ++p) {
                float h[2];
#pragma unroll
                for (int e = 0; e < 2; ++e) {
                    const int j = blk * 8 + p * 2 + e;
                    float a = b1[j];
                    a = fmaf(qv.x, W1[4 * j + 0], a);
                    a = fmaf(qv.y, W1[4 * j + 1], a);
                    a = fmaf(qv.z, W1[4 * j + 2], a);
                    a = fmaf(qv.w, W1[4 * j + 3], a);
                    h[e] = lrelu(a);
                }
                up[p] = pk_bf16(h[0], h[1]);
            }
            *(uint4*)(myrow + ((blk ^ sw) << 3)) = make_uint4(up[0], up[1], up[2], up[3]);
        }
    }
    // No barrier needed below: wave w touches only rows it wrote itself;
    // same-wave LDS ops complete in order (R5-validated).

    const int gbase = blockIdx.x * ROWS_PER_BLOCK + wv * 64;
    float* const pw = psum + wv * PW;
    float* const sw2 = s2 + wv * 64;

#pragma unroll 1
    for (int mt = 0; mt < 4; ++mt) {
        const int lrow = wv * 64 + mt * 16 + col;   // block-relative A-row
        // ---- A fragments (swizzled; R7-measured conflict-free) ------------
        const unsigned short* rowp = h1s + lrow * 64;
        const int sk = col & 7;                     // (lrow & 7) == (col & 7)
        const uint4 a0u = *(const uint4*)(rowp + (((quad)     ^ sk) << 3));
        const uint4 a1u = *(const uint4*)(rowp + (((quad + 4) ^ sk) << 3));
        const bf16x8 a0 = __builtin_bit_cast(bf16x8, a0u);
        const bf16x8 a1 = __builtin_bit_cast(bf16x8, a1u);

        // ---- layer 2: h2 tile (16x64), fp32 accumulators ------------------
        f32x4 acc[4];
#pragma unroll
        for (int t = 0; t < 4; ++t) {
            acc[t] = (f32x4){b2c[t], b2c[t], b2c[t], b2c[t]};
            acc[t] = __builtin_amdgcn_mfma_f32_16x16x32_bf16(a0, bfrag[t][0], acc[t], 0, 0, 0);
            acc[t] = __builtin_amdgcn_mfma_f32_16x16x32_bf16(a1, bfrag[t][1], acc[t], 0, 0, 0);
        }

        // ---- head partials over this lane's 4 cols -> psum slab -----------
#pragma unroll
        for (int r = 0; r < 4; ++r) {
            const float l0 = lrelu(acc[0][r]);
            const float l1 = lrelu(acc[1][r]);
            const float l2 = lrelu(acc[2][r]);
            const float l3 = lrelu(acc[3][r]);
            const float p0 = fmaf(l3, wld0[3], fmaf(l2, wld0[2], fmaf(l1, wld0[1], l0 * wld0[0])));
            const float p1 = fmaf(l3, wld1[3], fmaf(l2, wld1[2], fmaf(l1, wld1[1], l0 * wld1[0])));
            const float p2 = fmaf(l3, wlo[3],  fmaf(l2, wlo[2],  fmaf(l1, wlo[1],  l0 * wlo[0])));
            float* prow = pw + PSTRIDE * (quad * 4 + r) + col;
            prow[0]  = p0;
            prow[16] = p1;
            prow[32] = p2;
        }

        // ---- reduce 16 cols: lane l<48 owns (row = l&15, head = l>>4) -----
        if (lane < 48) {
            const int row = lane & 15;
            const int hh  = lane >> 4;
            const float* pr = pw + PSTRIDE * row + 16 * hh;
            float s = 0.0f;
#pragma unroll
            for (int j = 0; j < 4; ++j) {
                const float4 v = *(const float4*)(pr + 4 * j);
                s += (v.x + v.y) + (v.z + v.w);
            }
            s += (hh == 0) ? bld0 : ((hh == 1) ? bld1 : blo);
            if (hh < 2) s = softplus(s);
            sw2[row * 4 + hh] = s;
        }

        // ---- epilogue: lane l<16 owns row l; coalesced 256B store ---------
        if (lane < 16) {
            const float ld0 = sw2[lane * 4 + 0];
            const float ld1 = sw2[lane * 4 + 1];
            const float lo  = sw2[lane * 4 + 2];
            float4 o;
            o.x = fmaf(ld0, ld0, 1e-9f);                  // H00
            o.y = ld0 * lo;                               // H01
            o.z = o.y;                                    // H10
            o.w = fmaf(lo, lo, fmaf(ld1, ld1, 1e-9f));    // H11
            reinterpret_cast<float4*>(out)[gbase + mt * 16 + lane] = o;
        }
    }
}

// ---- scalar fallback for tail rows (nrows % 256) --------------------------
__global__ __launch_bounds__(256) void dln_tail(
    const float* __restrict__ x,
    const float* __restrict__ W1,  const float* __restrict__ b1,
    const float* __restrict__ W2,  const float* __restrict__ b2,
    const float* __restrict__ WLd, const float* __restrict__ bLd,
    const float* __restrict__ WLo, const float* __restrict__ bLo,
    float* __restrict__ out, int row0, int nrows)
{
    const int row = row0 + blockIdx.x * 256 + threadIdx.x;
    if (row >= nrows) return;
    const float4 qv = reinterpret_cast<const float4*>(x)[row];
    float h1[64];
#pragma unroll
    for (int j = 0; j < 64; ++j) {
        float a = b1[j];
        a = fmaf(qv.x, W1[4 * j + 0], a);
        a = fmaf(qv.y, W1[4 * j + 1], a);
        a = fmaf(qv.z, W1[4 * j + 2], a);
        a = fmaf(qv.w, W1[4 * j + 3], a);
        h1[j] = lrelu(a);
    }
    float ld0 = bLd[0], ld1 = bLd[1], lo = bLo[0];
#pragma unroll 4
    for (int j = 0; j < 64; ++j) {
        float a0 = b2[j], a1 = 0.0f;
        const float* w = W2 + 64 * j;
#pragma unroll
        for (int k = 0; k < 64; k += 2) {
            a0 = fmaf(h1[k],     w[k],     a0);
            a1 = fmaf(h1[k + 1], w[k + 1], a1);
        }
        const float a = lrelu(a0 + a1);
        ld0 = fmaf(a, WLd[j],      ld0);
        ld1 = fmaf(a, WLd[64 + j], ld1);
        lo  = fmaf(a, WLo[j],      lo);
    }
    ld0 = softplus(ld0);
    ld1 = softplus(ld1);
    float4 o;
    o.x = fmaf(ld0, ld0, 1e-9f);
    o.y = ld0 * lo;
    o.z = o.y;
    o.w = fmaf(lo, lo, fmaf(ld1, ld1, 1e-9f));
    reinterpret_cast<float4*>(out)[row] = o;
}

extern "C" void kernel_launch(void* const* d_in, const int* in_sizes, int n_in,
                              void* d_out, int out_size, void* d_ws, size_t ws_size,
                              hipStream_t stream)
{
    const float* x   = (const float*)d_in[0];
    const float* W1  = (const float*)d_in[1];
    const float* b1  = (const float*)d_in[2];
    const float* W2  = (const float*)d_in[3];
    const float* b2  = (const float*)d_in[4];
    const float* WLd = (const float*)d_in[5];
    const float* bLd = (const float*)d_in[6];
    const float* WLo = (const float*)d_in[7];
    const float* bLo = (const float*)d_in[8];
    float* out = (float*)d_out;

    const int nrows = in_sizes[0] / 4;             // x is (nrows, 4) fp32
    const int nfull = nrows / ROWS_PER_BLOCK;
    const int rem   = nrows - nfull * ROWS_PER_BLOCK;

    if (nfull > 0)
        dln_mfma<<<nfull, 256, 0, stream>>>(
            x, W1, b1, W2, b2, WLd, bLd, WLo, bLo, out);
    if (rem > 0)
        dln_tail<<<(rem + 255) / 256, 256, 0, stream>>>(
            x, W1, b1, W2, b2, WLd, bLd, WLo, bLo, out,
            nfull * ROWS_PER_BLOCK, nrows);
}

// Round 10
// 137.843 us; speedup vs baseline: 1.4731x; 1.0076x over previous
//
#include <hip/hip_runtime.h>

// ---------------------------------------------------------------------------
// DeepLagrangianNetwork head, MFMA v6 (R9 skeleton, B-frags from global).
//   prologue: B-frags packed from GLOBAL fp32 W2 (R7-proven: 0 LDS conflicts,
//             L1-hot, FETCH +~1MB only). No W2 LDS staging, NO barriers at all
//             (every LDS producer->consumer is same-wave; R5/R9-validated).
//   phase 1:  h1 = lrelu(q@W1^T+b1), thread-per-row, packed bf16 ->
//             XOR-swizzled LDS (stride 64 shorts; R7-measured 0 conflicts).
//   mt loop (per wave, 4 tiles of 16 rows):
//     A-frags from swizzled LDS -> 8x mfma_16x16x32_bf16 (fp32 acc)
//     head partials per lane -> fp32 LDS slab (stride 52: writes 2-way=free)
//     48 lanes reduce 16 cols; regroup via s2; 16 lanes: softplus +
//     H = L L^T + 1e-9 I, coalesced 256B float4 store.
//   h2 never materialized/quantized. R9-proven no-spill head path.
// Fragment layouts (m89-verified, R5..R9-validated):
//   A[m=lane&15][k=(lane>>4)*8+j] (+32)   B[k][n=lane&15]
//   C/D: n=lane&15, m=(lane>>4)*4+reg
// ---------------------------------------------------------------------------

typedef __attribute__((ext_vector_type(8))) short bf16x8;
typedef __attribute__((ext_vector_type(4))) float f32x4;

#define ROWS_PER_BLOCK 256
#define PSTRIDE 52                     // dwords per partial row (16B-aligned)
#define PW (PSTRIDE * 16)              // 832 dwords per wave

__device__ __forceinline__ float lrelu(float a) {
    return fmaxf(a, 0.01f * a);        // exact leaky_relu(0.01)
}

__device__ __forceinline__ float softplus(float v) {
    return fmaxf(v, 0.0f) + log1pf(expf(-fabsf(v)));   // jax.nn.softplus
}

__device__ __forceinline__ unsigned short bf16_rne(float f) {
    unsigned u = __float_as_uint(f);
    u += 0x7FFFu + ((u >> 16) & 1u);   // round-to-nearest-even
    return (unsigned short)(u >> 16);
}

__device__ __forceinline__ unsigned pk_bf16(float lo, float hi) {
    return (unsigned)bf16_rne(lo) | ((unsigned)bf16_rne(hi) << 16);
}

__global__ __launch_bounds__(256) void dln_mfma(
    const float* __restrict__ x,
    const float* __restrict__ W1,  const float* __restrict__ b1,
    const float* __restrict__ W2,  const float* __restrict__ b2,
    const float* __restrict__ WLd, const float* __restrict__ bLd,
    const float* __restrict__ WLo, const float* __restrict__ bLo,
    float* __restrict__ out)
{
    // h1: 256 rows x 64 shorts, XOR-swizzled (32 KB)
    __shared__ __align__(16) unsigned short h1s[ROWS_PER_BLOCK * 64];
    // per-wave head-partial slab: 16 rows x (3 heads x 16 cols), stride 52
    __shared__ __align__(16) float psum[4 * PW];          // 13312 B
    // per-wave regroup slab: 16 rows x 4
    __shared__ float s2[4 * 64];                          // 1 KB

    const int tid  = threadIdx.x;
    const int lane = tid & 63;
    const int wv   = tid >> 6;
    const int quad = lane >> 4;
    const int col  = lane & 15;

    // ---- per-lane loop invariants (L1-hot global) -------------------------
    float wld0[4], wld1[4], wlo[4], b2c[4];
#pragma unroll
    for (int t = 0; t < 4; ++t) {
        const int n = 16 * t + col;
        wld0[t] = WLd[n];
        wld1[t] = WLd[64 + n];
        wlo[t]  = WLo[n];
        b2c[t]  = b2[n];
    }
    const float bld0 = bLd[0], bld1 = bLd[1], blo = bLo[0];

    // ---- B fragments from GLOBAL W2 (R7 prologue; 0 LDS conflicts) --------
    // B[k][n] = W2[n][k], n = 16t+col, k = 32s + 8*quad + j
    bf16x8 bfrag[4][2];
#pragma unroll
    for (int t = 0; t < 4; ++t) {
#pragma unroll
        for (int s = 0; s < 2; ++s) {
            const float* p = W2 + (16 * t + col) * 64 + 32 * s + 8 * quad;
            const float4 f0 = *(const float4*)(p);
            const float4 f1 = *(const float4*)(p + 4);
            uint4 u;
            u.x = pk_bf16(f0.x, f0.y);
            u.y = pk_bf16(f0.z, f0.w);
            u.z = pk_bf16(f1.x, f1.y);
            u.w = pk_bf16(f1.z, f1.w);
            bfrag[t][s] = __builtin_bit_cast(bf16x8, u);
        }
    }

    // ---- phase 1: h1 for row = tid, packed bf16 -> swizzled LDS -----------
    {
        const int row_g = blockIdx.x * ROWS_PER_BLOCK + tid;
        const float4 qv = ((const float4*)x)[row_g];
        unsigned short* myrow = h1s + tid * 64;
        const int sw = tid & 7;                     // row XOR key
#pragma unroll
        for (int blk = 0; blk < 8; ++blk) {
            unsigned up[4];
#pragma unroll
            for (int p = 0; p < 4; ++p) {
                float h[2];
#pragma unroll
                for (int e = 0; e < 2; ++e) {
                    const int j = blk * 8 + p * 2 + e;
                    float a = b1[j];
                    a = fmaf(qv.x, W1[4 * j + 0], a);
                    a = fmaf(qv.y, W1[4 * j + 1], a);
                    a = fmaf(qv.z, W1[4 * j + 2], a);
                    a = fmaf(qv.w, W1[4 * j + 3], a);
                    h[e] = lrelu(a);
                }
                up[p] = pk_bf16(h[0], h[1]);
            }
            *(uint4*)(myrow + ((blk ^ sw) << 3)) = make_uint4(up[0], up[1], up[2], up[3]);
        }
    }
    // NO barriers anywhere: wave w touches only LDS it wrote itself;
    // same-wave LDS ops complete in order (R5/R9-validated).

    const int gbase = blockIdx.x * ROWS_PER_BLOCK + wv * 64;
    float* const pw  = psum + wv * PW;
    float* const sw2 = s2 + wv * 64;

#pragma unroll 1
    for (int mt = 0; mt < 4; ++mt) {
        const int lrow = wv * 64 + mt * 16 + col;   // block-relative A-row
        // ---- A fragments (swizzled; R7-measured conflict-free) ------------
        const unsigned short* rowp = h1s + lrow * 64;
        const int sk = col & 7;                     // (lrow & 7) == (col & 7)
        const uint4 a0u = *(const uint4*)(rowp + (((quad)     ^ sk) << 3));
        const uint4 a1u = *(const uint4*)(rowp + (((quad + 4) ^ sk) << 3));
        const bf16x8 a0 = __builtin_bit_cast(bf16x8, a0u);
        const bf16x8 a1 = __builtin_bit_cast(bf16x8, a1u);

        // ---- layer 2: h2 tile (16x64), fp32 accumulators ------------------
        f32x4 acc[4];
#pragma unroll
        for (int t = 0; t < 4; ++t) {
            acc[t] = (f32x4){b2c[t], b2c[t], b2c[t], b2c[t]};
            acc[t] = __builtin_amdgcn_mfma_f32_16x16x32_bf16(a0, bfrag[t][0], acc[t], 0, 0, 0);
            acc[t] = __builtin_amdgcn_mfma_f32_16x16x32_bf16(a1, bfrag[t][1], acc[t], 0, 0, 0);
        }

        // ---- head partials over this lane's 4 cols -> psum slab -----------
        // write banks: (16q + const) mod 32 -> 2-way aliasing only (free)
#pragma unroll
        for (int r = 0; r < 4; ++r) {
            const float l0 = lrelu(acc[0][r]);
            const float l1 = lrelu(acc[1][r]);
            const float l2 = lrelu(acc[2][r]);
            const float l3 = lrelu(acc[3][r]);
            const float p0 = fmaf(l3, wld0[3], fmaf(l2, wld0[2], fmaf(l1, wld0[1], l0 * wld0[0])));
            const float p1 = fmaf(l3, wld1[3], fmaf(l2, wld1[2], fmaf(l1, wld1[1], l0 * wld1[0])));
            const float p2 = fmaf(l3, wlo[3],  fmaf(l2, wlo[2],  fmaf(l1, wlo[1],  l0 * wlo[0])));
            float* prow = pw + PSTRIDE * (quad * 4 + r) + col;
            prow[0]  = p0;
            prow[16] = p1;
            prow[32] = p2;
        }

        // ---- reduce 16 cols: lane l<48 owns (row = l&15, head = l>>4) -----
        if (lane < 48) {
            const int row = lane & 15;
            const int hh  = lane >> 4;
            const float* pr = pw + PSTRIDE * row + 16 * hh;
            float s = 0.0f;
#pragma unroll
            for (int j = 0; j < 4; ++j) {
                const float4 v = *(const float4*)(pr + 4 * j);
                s += (v.x + v.y) + (v.z + v.w);
            }
            s += (hh == 0) ? bld0 : ((hh == 1) ? bld1 : blo);
            if (hh < 2) s = softplus(s);
            sw2[row * 4 + hh] = s;
        }

        // ---- epilogue: lane l<16 owns row l; coalesced 256B store ---------
        if (lane < 16) {
            const float ld0 = sw2[lane * 4 + 0];
            const float ld1 = sw2[lane * 4 + 1];
            const float lo  = sw2[lane * 4 + 2];
            float4 o;
            o.x = fmaf(ld0, ld0, 1e-9f);                  // H00
            o.y = ld0 * lo;                               // H01
            o.z = o.y;                                    // H10
            o.w = fmaf(lo, lo, fmaf(ld1, ld1, 1e-9f));    // H11
            reinterpret_cast<float4*>(out)[gbase + mt * 16 + lane] = o;
        }
    }
}

// ---- scalar fallback for tail rows (nrows % 256) --------------------------
__global__ __launch_bounds__(256) void dln_tail(
    const float* __restrict__ x,
    const float* __restrict__ W1,  const float* __restrict__ b1,
    const float* __restrict__ W2,  const float* __restrict__ b2,
    const float* __restrict__ WLd, const float* __restrict__ bLd,
    const float* __restrict__ WLo, const float* __restrict__ bLo,
    float* __restrict__ out, int row0, int nrows)
{
    const int row = row0 + blockIdx.x * 256 + threadIdx.x;
    if (row >= nrows) return;
    const float4 qv = reinterpret_cast<const float4*>(x)[row];
    float h1[64];
#pragma unroll
    for (int j = 0; j < 64; ++j) {
        float a = b1[j];
        a = fmaf(qv.x, W1[4 * j + 0], a);
        a = fmaf(qv.y, W1[4 * j + 1], a);
        a = fmaf(qv.z, W1[4 * j + 2], a);
        a = fmaf(qv.w, W1[4 * j + 3], a);
        h1[j] = lrelu(a);
    }
    float ld0 = bLd[0], ld1 = bLd[1], lo = bLo[0];
#pragma unroll 4
    for (int j = 0; j < 64; ++j) {
        float a0 = b2[j], a1 = 0.0f;
        const float* w = W2 + 64 * j;
#pragma unroll
        for (int k = 0; k < 64; k += 2) {
            a0 = fmaf(h1[k],     w[k],     a0);
            a1 = fmaf(h1[k + 1], w[k + 1], a1);
        }
        const float a = lrelu(a0 + a1);
        ld0 = fmaf(a, WLd[j],      ld0);
        ld1 = fmaf(a, WLd[64 + j], ld1);
        lo  = fmaf(a, WLo[j],      lo);
    }
    ld0 = softplus(ld0);
    ld1 = softplus(ld1);
    float4 o;
    o.x = fmaf(ld0, ld0, 1e-9f);
    o.y = ld0 * lo;
    o.z = o.y;
    o.w = fmaf(lo, lo, fmaf(ld1, ld1, 1e-9f));
    reinterpret_cast<float4*>(out)[row] = o;
}

extern "C" void kernel_launch(void* const* d_in, const int* in_sizes, int n_in,
                              void* d_out, int out_size, void* d_ws, size_t ws_size,
                              hipStream_t stream)
{
    const float* x   = (const float*)d_in[0];
    const float* W1  = (const float*)d_in[1];
    const float* b1  = (const float*)d_in[2];
    const float* W2  = (const float*)d_in[3];
    const float* b2  = (const float*)d_in[4];
    const float* WLd = (const float*)d_in[5];
    const float* bLd = (const float*)d_in[6];
    const float* WLo = (const float*)d_in[7];
    const float* bLo = (const float*)d_in[8];
    float* out = (float*)d_out;

    const int nrows = in_sizes[0] / 4;             // x is (nrows, 4) fp32
    const int nfull = nrows / ROWS_PER_BLOCK;
    const int rem   = nrows - nfull * ROWS_PER_BLOCK;

    if (nfull > 0)
        dln_mfma<<<nfull, 256, 0, stream>>>(
            x, W1, b1, W2, b2, WLd, bLd, WLo, bLo, out);
    if (rem > 0)
        dln_tail<<<(rem + 255) / 256, 256, 0, stream>>>(
            x, W1, b1, W2, b2, WLd, bLd, WLo, bLo, out,
            nfull * ROWS_PER_BLOCK, nrows);
}